// Round 9
// baseline (219.740 us; speedup 1.0000x reference)
//
#include <hip/hip_runtime.h>

typedef unsigned int u32;
typedef unsigned short u16;
typedef __attribute__((ext_vector_type(4))) float fx4;
typedef __attribute__((ext_vector_type(8))) short s16x8;
typedef __attribute__((ext_vector_type(4))) u32 u32x4;

#define DD 128
#define KK 1024

__device__ __forceinline__ u16 f2bf(float f) {
  u32 u = __float_as_uint(f);
  return (u16)((u + 0x7FFFu + ((u >> 16) & 1u)) >> 16);
}
__device__ __forceinline__ u32 umin32(u32 a, u32 b) { return a < b ? a : b; }

// packed bf16 RNE convert: bf16(lo) -> bits[15:0], bf16(hi) -> bits[31:16]
__device__ __forceinline__ u32 cvtpk(float lo, float hi) {
  u32 r;
  asm("v_cvt_pk_bf16_f32 %0, %1, %2" : "=v"(r) : "v"(lo), "v"(hi));
  return r;
}
// same, with free VOP3 neg modifiers on both inputs
__device__ __forceinline__ u32 cvtpkn(float lo, float hi) {
  u32 r;
  asm("v_cvt_pk_bf16_f32 %0, -%1, -%2" : "=v"(r) : "v"(lo), "v"(hi));
  return r;
}
__device__ __forceinline__ s16x8 as_s16x8(u32x4 v) {
  union { u32x4 u; s16x8 s; } x;
  x.u = v;
  return x.s;
}
// async global->LDS DMA, 16B per lane; LDS dest is wave-uniform base + lane*16
__device__ __forceinline__ void gll16(const void* g, void* l) {
  __builtin_amdgcn_global_load_lds(
      (const __attribute__((address_space(1))) unsigned int*)g,
      (__attribute__((address_space(3))) unsigned int*)l, 16, 0, 0);
}

// ---------------- prep: cbf fp32 -> bf16 (RTN, bit-identical to prior rounds),
// k-major cbt: [lvl(4)][ku(16)][col(1024)][8] u16 (1 MiB). 256 blocks x 64 thr,
// block = 16 codewords. Also zeroes the loss slot in d_out. (unchanged)
extern "C" __global__ __launch_bounds__(64) void rvq_prep(
    const float* __restrict__ cbf, u16* __restrict__ cbt,
    float* __restrict__ lossout) {
  if (blockIdx.x == 0 && threadIdx.x == 0) lossout[0] = 0.f;
  const int cl = threadIdx.x >> 2, dq = threadIdx.x & 3;
  const int cw = blockIdx.x * 16 + cl;
  const int lvl = cw >> 10, colg = cw & 1023;
  const float* src = cbf + (size_t)cw * DD + dq * 32;
  u32x4* dst = (u32x4*)cbt;
#pragma unroll
  for (int k8 = 0; k8 < 4; ++k8) {
    const fx4 a = *(const fx4*)(src + k8 * 8);
    const fx4 b = *(const fx4*)(src + k8 * 8 + 4);
    u32x4 pk;
    pk.x = (u32)f2bf(a[0]) | ((u32)f2bf(a[1]) << 16);
    pk.y = (u32)f2bf(a[2]) | ((u32)f2bf(a[3]) << 16);
    pk.z = (u32)f2bf(b[0]) | ((u32)f2bf(b[1]) << 16);
    pk.w = (u32)f2bf(b[2]) | ((u32)f2bf(b[3]) << 16);
    dst[((lvl * 16 + dq * 4 + k8) * 1024) + colg] = pk;  // 1 KB-coalesced across block
  }
}

// ---------------- main: 512 blocks x 256 thr; block = 64 rows x 1024 cols.
// vs r4 (79.4us champion): B-frags no longer stream into REGISTER buffers —
// the K-loop stages each 64-col tile (16 KB) into a double-buffered LDS ring
// via global_load_lds (no dest regs, fully-coalesced 1KB/wave), with raw
// s_barrier + COUNTED vmcnt(4) (never a drain in the loop; T3/T4 pattern).
// Rationale: r4's wall tracks per-block LOAD VOLUME (r7: 2x loads -> 1.55x
// wall) and MfmaUtil 17.6% == pipe-floor/wall — the register-dest loads'
// vmcnt waits serialize the wave (depth 1->3 bought only 6.5% because the
// compiler's wait placement collapses effective depth). DMA staging removes
// that class entirely AND frees 64 B-buffer regs (total ~120 < 128, margin
// at the boundary phases instead of r5/r8's spill).
// Xlds dropped for LDS budget (33.8 Rlds + 32 stage + 1 lmin = 67.6 KB -> 2
// blocks/CU); final level re-reads x from HBM (+16.8 MB, ~3us, overlapped).
// Cross-level: KSTEP 15 stages the NEXT level's tile 0 (free lead across the
// boundary phase). Ledger: r1/2/6 bound-spill; r3 tile-split tail; r5/r8
// +16-reg spill; r7 clean 8-wave still lost (TLP not the remedy).
extern "C" __global__ __launch_bounds__(256, 2) void rvq_main(
    const float* __restrict__ x, const float* __restrict__ cbf,
    const u16* __restrict__ cbt, float* __restrict__ yout,
    float* __restrict__ lossacc) {
  __shared__ float Rlds[64][132];   // negated residual; +4 pad
  __shared__ u32x4 Bst[2][1024];    // staging ring: [buf][ku(16)*64 + col(64)]
  __shared__ u32 lmin[64][4];       // [row][wave]

  const int tid = threadIdx.x;
  const int wv = tid >> 6, lane = tid & 63;
  const int c = lane & 15, q = lane >> 4;
  const int rowbase = blockIdx.x * 64;
  const int rot = (int)((blockIdx.x >> 3) & 15);  // de-lockstep same-XCD L2 streams
  const s16x8* cbt16 = (const s16x8*)cbt;         // 16B units: [lvl][ku][col]

  s16x8 afr[4][4];  // A-frags: afr[t][s] -> rows t*16+c, k = s*32 + q*8 + j
#pragma unroll
  for (int t = 0; t < 4; ++t) {
    const float* xr = x + (size_t)(rowbase + t * 16 + c) * DD + q * 8;
#pragma unroll
    for (int s = 0; s < 4; ++s) {
      const fx4 a = *(const fx4*)(xr + s * 32);
      const fx4 b = *(const fx4*)(xr + s * 32 + 4);
      u32x4 af;
      af.x = cvtpkn(a[0], a[1]);
      af.y = cvtpkn(a[2], a[3]);
      af.z = cvtpkn(b[0], b[1]);
      af.w = cvtpkn(b[2], b[3]);
      afr[t][s] = as_s16x8(af);
      if (t == wv) {  // wave wv owns Rlds rows wv*16..wv*16+15
        fx4 na, nb;
#pragma unroll
        for (int j = 0; j < 4; ++j) { na[j] = -a[j]; nb[j] = -b[j]; }
        *(fx4*)&Rlds[t * 16 + c][s * 32 + q * 8] = na;
        *(fx4*)&Rlds[t * 16 + c][s * 32 + q * 8 + 4] = nb;
      }
    }
  }

  // Stage tile g=0 (lvl 0, tk = rot) into buf 0.
  // Per wave per round it: 64 contiguous units (1 KB) — fully coalesced.
  // LDS unit u = it*256 + wv*64 + lane holds cbt unit [ku=it*4+wv][tk*64+lane].
  {
    const s16x8* srcb = cbt16 + ((0 + rot) & 15) * 64 + lane;
#pragma unroll
    for (int it = 0; it < 4; ++it)
      gll16(srcb + (it * 4 + wv) * 1024, &Bst[0][it * 256 + wv * 64]);
  }

  u32 run[4][4];
#pragma unroll
  for (int t = 0; t < 4; ++t)
#pragma unroll
    for (int r = 0; r < 4; ++r) run[t][r] = 0xFFFFFFFFu;

  float lsum = 0.f;

#pragma unroll 1
  for (int lvl = 0; lvl < 4; ++lvl) {
    // acc = 0.75 - r.c  in (0.625, 0.875) [|r.c| <= ~0.04, wrap-safe to 0.125]
    // key = (bits(acc)<<10) + col - 2^31 : monotone, ties -> lowest col.
    // Per KSTEP(CT): buf=CT&1. Issue staging of tile g+1 into buf^1 (CT==15:
    // next level's tile 0); counted vmcnt(4) -> own part of tile g staged;
    // s_barrier -> tile g complete across waves; ds_read 4x b128 frags; MFMA;
    // key flush; s_barrier -> all reads done, buf safe to overwrite next step.
#define KSTEP(CT)                                                                  \
  {                                                                                \
    const int bufc = (CT) & 1;                                                     \
    if (lvl == 3 && (CT) == 15) {                                                  \
      asm volatile("s_waitcnt vmcnt(0)" ::: "memory");                             \
    } else {                                                                       \
      const int lvn = lvl + (((CT) == 15) ? 1 : 0);                                \
      const int tkn = ((((CT) + 1) & 15) + rot) & 15;                              \
      const s16x8* srcb = cbt16 + lvn * 16384 + tkn * 64 + lane;                   \
      _Pragma("unroll") for (int it = 0; it < 4; ++it)                             \
          gll16(srcb + (it * 4 + wv) * 1024, &Bst[bufc ^ 1][it * 256 + wv * 64]);  \
      asm volatile("s_waitcnt vmcnt(4)" ::: "memory");                             \
    }                                                                              \
    __builtin_amdgcn_s_barrier();                                                  \
    s16x8 bfr[4];                                                                  \
    _Pragma("unroll") for (int s5 = 0; s5 < 4; ++s5)                               \
        bfr[s5] = *(const s16x8*)&Bst[bufc][(s5 * 4 + q) * 64 + wv * 16 + c];      \
    const u32 kadd = (u32)(((((CT) + rot) & 15) * 64) + wv * 16 + c) - 0x80000000u;\
    fx4 ac0 = {0.75f, 0.75f, 0.75f, 0.75f};                                        \
    fx4 ac1 = ac0, ac2 = ac0, ac3 = ac0;                                           \
    _Pragma("unroll") for (int s5 = 0; s5 < 4; ++s5) {                             \
      const s16x8 bfrag = bfr[s5];                                                 \
      ac0 = __builtin_amdgcn_mfma_f32_16x16x32_bf16(afr[0][s5], bfrag, ac0, 0, 0, 0); \
      ac1 = __builtin_amdgcn_mfma_f32_16x16x32_bf16(afr[1][s5], bfrag, ac1, 0, 0, 0); \
      ac2 = __builtin_amdgcn_mfma_f32_16x16x32_bf16(afr[2][s5], bfrag, ac2, 0, 0, 0); \
      ac3 = __builtin_amdgcn_mfma_f32_16x16x32_bf16(afr[3][s5], bfrag, ac3, 0, 0, 0); \
    }                                                                              \
    _Pragma("unroll") for (int r5 = 0; r5 < 4; ++r5) {                             \
      run[0][r5] = umin32(run[0][r5], (__float_as_uint(ac0[r5]) << 10) + kadd);    \
      run[1][r5] = umin32(run[1][r5], (__float_as_uint(ac1[r5]) << 10) + kadd);    \
      run[2][r5] = umin32(run[2][r5], (__float_as_uint(ac2[r5]) << 10) + kadd);    \
      run[3][r5] = umin32(run[3][r5], (__float_as_uint(ac3[r5]) << 10) + kadd);    \
    }                                                                              \
    __builtin_amdgcn_s_barrier();                                                  \
  }
    KSTEP(0)  KSTEP(1)  KSTEP(2)  KSTEP(3)
    KSTEP(4)  KSTEP(5)  KSTEP(6)  KSTEP(7)
    KSTEP(8)  KSTEP(9)  KSTEP(10) KSTEP(11)
    KSTEP(12) KSTEP(13) KSTEP(14) KSTEP(15)
#undef KSTEP

    // reduce over the 16 c-lanes (row lives on q*4+r within tile t)
#pragma unroll
    for (int m = 1; m < 16; m <<= 1)
#pragma unroll
      for (int t = 0; t < 4; ++t)
#pragma unroll
        for (int r = 0; r < 4; ++r)
          run[t][r] = umin32(run[t][r], (u32)__shfl_xor((int)run[t][r], m, 64));
    if (c == 0) {
#pragma unroll
      for (int t = 0; t < 4; ++t)
#pragma unroll
        for (int r = 0; r < 4; ++r)
          lmin[t * 16 + q * 4 + r][wv] = run[t][r];
    }
    __syncthreads();  // lmin complete across the 4 waves

    // update own rows: row = wv*16 + c, dims q*32..q*32+31 (exact fp32 codebook)
    const int row = wv * 16 + c;
    const u32x4 p = *(const u32x4*)&lmin[row][0];
    const u32 pm = umin32(umin32(p.x, p.y), umin32(p.z, p.w));
    const int col = (int)(pm & 1023u);
    const float* qp = cbf + ((size_t)lvl * KK + col) * DD + q * 32;
    float* Rr = &Rlds[row][q * 32];
    if (lvl < 3) {
#pragma unroll
      for (int k4 = 0; k4 < 8; ++k4) {
        fx4 rv = *(const fx4*)(Rr + k4 * 4);
        const fx4 qv = *(const fx4*)(qp + k4 * 4);
#pragma unroll
        for (int j = 0; j < 4; ++j) { rv[j] += qv[j]; lsum = fmaf(rv[j], rv[j], lsum); }
        *(fx4*)(Rr + k4 * 4) = rv;
      }
      __syncthreads();  // new residual visible; also orders lmin reads vs next level
      // rebuild all 64 rows' A-frags from Rlds; reset keys
#pragma unroll
      for (int t = 0; t < 4; ++t)
#pragma unroll
        for (int s = 0; s < 4; ++s) {
          const fx4 r0 = *(const fx4*)&Rlds[t * 16 + c][s * 32 + q * 8];
          const fx4 r1 = *(const fx4*)&Rlds[t * 16 + c][s * 32 + q * 8 + 4];
          u32x4 af;
          af.x = cvtpk(r0[0], r0[1]);
          af.y = cvtpk(r0[2], r0[3]);
          af.z = cvtpk(r1[0], r1[1]);
          af.w = cvtpk(r1[2], r1[3]);
          afr[t][s] = as_s16x8(af);
        }
#pragma unroll
      for (int t = 0; t < 4; ++t)
#pragma unroll
        for (int r = 0; r < 4; ++r) run[t][r] = 0xFFFFFFFFu;
    } else {  // final level: y = x + R_final (forward value = q_sum), x from HBM
      const size_t gb = (size_t)(rowbase + row) * DD + q * 32;
#pragma unroll
      for (int k4 = 0; k4 < 8; ++k4) {
        fx4 rv = *(const fx4*)(Rr + k4 * 4);
        const fx4 qv = *(const fx4*)(qp + k4 * 4);
        const fx4 xv = *(const fx4*)(x + gb + k4 * 4);
        fx4 yv;
#pragma unroll
        for (int j = 0; j < 4; ++j) {
          rv[j] += qv[j];
          lsum = fmaf(rv[j], rv[j], lsum);
          yv[j] = xv[j] + rv[j];
        }
        *(fx4*)(yout + gb + k4 * 4) = yv;
      }
    }
  }

#pragma unroll
  for (int m = 32; m >= 1; m >>= 1) lsum += __shfl_xor(lsum, m, 64);
  if (lane == 0) atomicAdd(lossacc, lsum * (1.25f / 4194304.f));  // 1.25/(N*D)
}

extern "C" void kernel_launch(void* const* d_in, const int* in_sizes, int n_in,
                              void* d_out, int out_size, void* d_ws, size_t ws_size,
                              hipStream_t stream) {
  const float* x = (const float*)d_in[0];     // [32768,128]
  const float* cbf = (const float*)d_in[1];   // [4,1024,128]
  float* y = (float*)d_out;
  float* lossout = y + (out_size - 1);
  u16* cbt = (u16*)d_ws;                      // 1 MiB k-major bf16 codebook

  rvq_prep<<<256, 64, 0, stream>>>(cbf, cbt, lossout);
  rvq_main<<<512, 256, 0, stream>>>(x, cbf, cbt, y, lossout);
}

// Round 10
// 154.491 us; speedup vs baseline: 1.4223x; 1.4223x over previous
//
#include <hip/hip_runtime.h>

typedef unsigned int u32;
typedef unsigned short u16;
typedef __attribute__((ext_vector_type(4))) float fx4;
typedef __attribute__((ext_vector_type(8))) short s16x8;
typedef __attribute__((ext_vector_type(4))) u32 u32x4;

#define DD 128
#define KK 1024

__device__ __forceinline__ u16 f2bf(float f) {
  u32 u = __float_as_uint(f);
  return (u16)((u + 0x7FFFu + ((u >> 16) & 1u)) >> 16);
}
__device__ __forceinline__ u32 umin32(u32 a, u32 b) { return a < b ? a : b; }

// packed bf16 RNE convert: bf16(lo) -> bits[15:0], bf16(hi) -> bits[31:16]
__device__ __forceinline__ u32 cvtpk(float lo, float hi) {
  u32 r;
  asm("v_cvt_pk_bf16_f32 %0, %1, %2" : "=v"(r) : "v"(lo), "v"(hi));
  return r;
}
// same, with free VOP3 neg modifiers on both inputs
__device__ __forceinline__ u32 cvtpkn(float lo, float hi) {
  u32 r;
  asm("v_cvt_pk_bf16_f32 %0, -%1, -%2" : "=v"(r) : "v"(lo), "v"(hi));
  return r;
}
__device__ __forceinline__ s16x8 as_s16x8(u32x4 v) {
  union { u32x4 u; s16x8 s; } x;
  x.u = v;
  return x.s;
}

// ---------------- prep: cbf fp32 -> bf16 (RTN, bit-identical to prior rounds),
// k-major cbt: [lvl(4)][ku(16)][col(1024)][8] u16 (1 MiB). 256 blocks x 64 thr,
// block = 16 codewords. Also zeroes the loss slot in d_out. (unchanged)
extern "C" __global__ __launch_bounds__(64) void rvq_prep(
    const float* __restrict__ cbf, u16* __restrict__ cbt,
    float* __restrict__ lossout) {
  if (blockIdx.x == 0 && threadIdx.x == 0) lossout[0] = 0.f;
  const int cl = threadIdx.x >> 2, dq = threadIdx.x & 3;
  const int cw = blockIdx.x * 16 + cl;
  const int lvl = cw >> 10, colg = cw & 1023;
  const float* src = cbf + (size_t)cw * DD + dq * 32;
  u32x4* dst = (u32x4*)cbt;
#pragma unroll
  for (int k8 = 0; k8 < 4; ++k8) {
    const fx4 a = *(const fx4*)(src + k8 * 8);
    const fx4 b = *(const fx4*)(src + k8 * 8 + 4);
    u32x4 pk;
    pk.x = (u32)f2bf(a[0]) | ((u32)f2bf(a[1]) << 16);
    pk.y = (u32)f2bf(a[2]) | ((u32)f2bf(a[3]) << 16);
    pk.z = (u32)f2bf(b[0]) | ((u32)f2bf(b[1]) << 16);
    pk.w = (u32)f2bf(b[2]) | ((u32)f2bf(b[3]) << 16);
    dst[((lvl * 16 + dq * 4 + k8) * 1024) + colg] = pk;  // 1 KB-coalesced across block
  }
}

// ---------------- main: 512 blocks x 256 thr; block = 64 rows x 1024 cols.
// This is the r5 kernel (deferred key-flush acc ping-pong + full cross-level
// prefetch + setprio on MFMA clusters) under __launch_bounds__(256, 1).
//
// REGISTER-BUDGET LAW (rounds 0-9): the allocator targets budget =
// 256/min_waves_arg and SPILLS to meet it, independent of true need:
// (.,2)->128 (r0/r4/r5/r8), (256,3)->84 (r3), (.,4)->64 (r1/r2/r6), each
// confirmed by VGPR_Count + FETCH/WRITE scratch inflation whenever live
// state exceeded the budget. Hardware occupancy follows USAGE (waves/CU
// halve at 64/128/256 regs), and this config is grid-limited to 8 waves/CU
// anyway (2 blocks x 4 waves), which is granted at ANY vgpr<=256. So regs
// 129..256 are FREE here — (256,1) sets budget 256 and un-spills r5's
// ~175-reg working set (accE/accO ping-pong + 4 rotating B buffers live
// across the level boundary).
// r5 mechanisms (all traffic/numerics-identical to r4):
//  (a) deferred key-update ping-pong: step N's key-min flush issues after
//      step N+1's MFMAs — MFMA->VALU result drain + 32 key ops hide under
//      the next step's matrix-pipe time (the serial chain that r4's counters
//      showed: wall ~2650 cyc vs ~630 pipe, 2 waves/SIMD can't fill it).
//  (b) cross-level prefetch: KSTEPs 13-15 load the NEXT level's blocks
//      0..2 — every level starts with 3 warm buffers, no cold-start stall.
//  (c) s_setprio(1) around MFMA clusters (barrier-free independent waves —
//      the attn-like regime where setprio pays).
// Ledger: r3 small tiles = 2x codebook traffic + residency tail; r7 clean
// 8-wave = TLP not the remedy; r9 gll+2-barrier staging = 400MB anomaly.
extern "C" __global__ __launch_bounds__(256, 1) void rvq_main(
    const float* __restrict__ x, const float* __restrict__ cbf,
    const u16* __restrict__ cbt, float* __restrict__ yout,
    float* __restrict__ lossacc) {
  __shared__ float Rlds[64][132];  // negated residual, single copy; +4 pad
  __shared__ float Xlds[64][132];  // raw x tile (final level: y = x + R)
  __shared__ u32 lmin[64][4];      // [row][wave]

  const int tid = threadIdx.x;
  const int wv = tid >> 6, lane = tid & 63;
  const int c = lane & 15, q = lane >> 4;
  const int rowbase = blockIdx.x * 64;
  const int rot = (int)((blockIdx.x >> 3) & 15);  // de-lockstep same-XCD L2 streams
  const s16x8* cbt16 = (const s16x8*)cbt;         // 16B units: [lvl][ku][col]

  s16x8 afr[4][4];  // A-frags: afr[t][s] -> rows t*16+c, k = s*32 + q*8 + j
#pragma unroll
  for (int t = 0; t < 4; ++t) {
    const float* xr = x + (size_t)(rowbase + t * 16 + c) * DD + q * 8;
#pragma unroll
    for (int s = 0; s < 4; ++s) {
      const fx4 a = *(const fx4*)(xr + s * 32);
      const fx4 b = *(const fx4*)(xr + s * 32 + 4);
      u32x4 af;
      af.x = cvtpkn(a[0], a[1]);
      af.y = cvtpkn(a[2], a[3]);
      af.z = cvtpkn(b[0], b[1]);
      af.w = cvtpkn(b[2], b[3]);
      afr[t][s] = as_s16x8(af);
      if (t == wv) {  // wave wv owns rows wv*16..wv*16+15 of Rlds AND Xlds
        fx4 na, nb;
#pragma unroll
        for (int j = 0; j < 4; ++j) { na[j] = -a[j]; nb[j] = -b[j]; }
        *(fx4*)&Rlds[t * 16 + c][s * 32 + q * 8] = na;
        *(fx4*)&Rlds[t * 16 + c][s * 32 + q * 8 + 4] = nb;
        *(fx4*)&Xlds[t * 16 + c][s * 32 + q * 8] = a;
        *(fx4*)&Xlds[t * 16 + c][s * 32 + q * 8 + 4] = b;
      }
    }
  }

  u32 run[4][4];
#pragma unroll
  for (int t = 0; t < 4; ++t)
#pragma unroll
    for (int r = 0; r < 4; ++r) run[t][r] = 0xFFFFFFFFu;

  float lsum = 0.f;

  // Depth-3 rotating B buffers, warm-started for level 0; carried across
  // levels via the CT=13..15 cross-level prefetch (no level-top refill).
  s16x8 brA[4], brB[4], brC[4], brD[4];
  {
    const s16x8* cl0 = cbt16 + q * 1024 + c;
    const int cb0 = ((rot) & 15) * 64 + wv * 16;
    const int cb1 = (((rot + 1) & 15) * 64) + wv * 16;
    const int cb2 = (((rot + 2) & 15) * 64) + wv * 16;
#pragma unroll
    for (int s5 = 0; s5 < 4; ++s5) {
      brA[s5] = cl0[s5 * 4096 + cb0];
      brB[s5] = cl0[s5 * 4096 + cb1];
      brC[s5] = cl0[s5 * 4096 + cb2];
    }
  }

#pragma unroll 1
  for (int lvl = 0; lvl < 4; ++lvl) {
    const s16x8* cl = cbt16 + lvl * 16384 + q * 1024 + c;   // this level
    const s16x8* cln = cbt16 + (lvl < 3 ? lvl + 1 : lvl) * 16384 + q * 1024 + c;  // next
    // acc = 0.75 - r.c  in (0.625, 0.875) [|r.c| <= ~0.04 here, wrap-safe to 0.125]
    // key = (bits(acc)<<10) + col - 2^31 : monotone, ties -> lowest col.
    // Step CT consumes buf[CT&3], prefetches buf[(CT+3)&3]: this level for
    // CT<13, NEXT level's blocks 0..2 for CT=13..15 (same rotation slots).
    // Key flush of step CT-1 (ACC_P, kaddP) issues after step CT's MFMAs.
    fx4 accE[4], accO[4];
    u32 kaddP = 0;
#define KSTEP(CUR, NXT, ACC_C, ACC_P, CT)                                          \
  {                                                                                \
    {                                                                              \
      const s16x8* pp = ((CT) < 13) ? cl : cln;                                    \
      const int cbn = ((((CT) + 3 + rot) & 15) * 64) + wv * 16;                    \
      _Pragma("unroll") for (int s5 = 0; s5 < 4; ++s5)                             \
          NXT[s5] = pp[s5 * 4096 + cbn];                                           \
    }                                                                              \
    _Pragma("unroll") for (int t5 = 0; t5 < 4; ++t5)                               \
      ACC_C[t5] = (fx4){0.75f, 0.75f, 0.75f, 0.75f};                               \
    __builtin_amdgcn_s_setprio(1);                                                 \
    _Pragma("unroll") for (int s5 = 0; s5 < 4; ++s5) {                             \
      const s16x8 bfrag = CUR[s5];                                                 \
      ACC_C[0] = __builtin_amdgcn_mfma_f32_16x16x32_bf16(afr[0][s5], bfrag, ACC_C[0], 0, 0, 0); \
      ACC_C[1] = __builtin_amdgcn_mfma_f32_16x16x32_bf16(afr[1][s5], bfrag, ACC_C[1], 0, 0, 0); \
      ACC_C[2] = __builtin_amdgcn_mfma_f32_16x16x32_bf16(afr[2][s5], bfrag, ACC_C[2], 0, 0, 0); \
      ACC_C[3] = __builtin_amdgcn_mfma_f32_16x16x32_bf16(afr[3][s5], bfrag, ACC_C[3], 0, 0, 0); \
    }                                                                              \
    __builtin_amdgcn_s_setprio(0);                                                 \
    if ((CT) > 0) {                                                                \
      _Pragma("unroll") for (int t5 = 0; t5 < 4; ++t5)                             \
        _Pragma("unroll") for (int r5 = 0; r5 < 4; ++r5)                           \
          run[t5][r5] = umin32(run[t5][r5],                                        \
                               (__float_as_uint(ACC_P[t5][r5]) << 10) + kaddP);    \
    }                                                                              \
    kaddP = (u32)(((((CT) + rot) & 15) * 64) + wv * 16 + c) - 0x80000000u;         \
  }
    KSTEP(brA, brD, accE, accO, 0)  KSTEP(brB, brA, accO, accE, 1)
    KSTEP(brC, brB, accE, accO, 2)  KSTEP(brD, brC, accO, accE, 3)
    KSTEP(brA, brD, accE, accO, 4)  KSTEP(brB, brA, accO, accE, 5)
    KSTEP(brC, brB, accE, accO, 6)  KSTEP(brD, brC, accO, accE, 7)
    KSTEP(brA, brD, accE, accO, 8)  KSTEP(brB, brA, accO, accE, 9)
    KSTEP(brC, brB, accE, accO, 10) KSTEP(brD, brC, accO, accE, 11)
    KSTEP(brA, brD, accE, accO, 12) KSTEP(brB, brA, accO, accE, 13)
    KSTEP(brC, brB, accE, accO, 14) KSTEP(brD, brC, accO, accE, 15)
#undef KSTEP
    // flush step 15 (accO, kaddP from CT=15)
#pragma unroll
    for (int t5 = 0; t5 < 4; ++t5)
#pragma unroll
      for (int r5 = 0; r5 < 4; ++r5)
        run[t5][r5] = umin32(run[t5][r5],
                             (__float_as_uint(accO[t5][r5]) << 10) + kaddP);

    // reduce over the 16 c-lanes (row lives on q*4+r within tile t)
#pragma unroll
    for (int m = 1; m < 16; m <<= 1)
#pragma unroll
      for (int t = 0; t < 4; ++t)
#pragma unroll
        for (int r = 0; r < 4; ++r)
          run[t][r] = umin32(run[t][r], (u32)__shfl_xor((int)run[t][r], m, 64));
    if (c == 0) {
#pragma unroll
      for (int t = 0; t < 4; ++t)
#pragma unroll
        for (int r = 0; r < 4; ++r)
          lmin[t * 16 + q * 4 + r][wv] = run[t][r];
    }
    __syncthreads();  // lmin complete across the 4 waves

    // update own rows: row = wv*16 + c, dims q*32..q*32+31 (exact fp32 codebook)
    const int row = wv * 16 + c;
    const u32x4 p = *(const u32x4*)&lmin[row][0];
    const u32 pm = umin32(umin32(p.x, p.y), umin32(p.z, p.w));
    const int col = (int)(pm & 1023u);
    const float* qp = cbf + ((size_t)lvl * KK + col) * DD + q * 32;
    float* Rr = &Rlds[row][q * 32];
    if (lvl < 3) {
#pragma unroll
      for (int k4 = 0; k4 < 8; ++k4) {
        fx4 rv = *(const fx4*)(Rr + k4 * 4);
        const fx4 qv = *(const fx4*)(qp + k4 * 4);
#pragma unroll
        for (int j = 0; j < 4; ++j) { rv[j] += qv[j]; lsum = fmaf(rv[j], rv[j], lsum); }
        *(fx4*)(Rr + k4 * 4) = rv;
      }
      __syncthreads();  // new residual visible; also orders lmin reads vs next level
      // rebuild all 64 rows' A-frags from Rlds; reset keys
#pragma unroll
      for (int t = 0; t < 4; ++t)
#pragma unroll
        for (int s = 0; s < 4; ++s) {
          const fx4 r0 = *(const fx4*)&Rlds[t * 16 + c][s * 32 + q * 8];
          const fx4 r1 = *(const fx4*)&Rlds[t * 16 + c][s * 32 + q * 8 + 4];
          u32x4 af;
          af.x = cvtpk(r0[0], r0[1]);
          af.y = cvtpk(r0[2], r0[3]);
          af.z = cvtpk(r1[0], r1[1]);
          af.w = cvtpk(r1[2], r1[3]);
          afr[t][s] = as_s16x8(af);
        }
#pragma unroll
      for (int t = 0; t < 4; ++t)
#pragma unroll
        for (int r = 0; r < 4; ++r) run[t][r] = 0xFFFFFFFFu;
    } else {  // final level: y = x + R_final (forward value = q_sum), x from Xlds
      const size_t gb = (size_t)(rowbase + row) * DD + q * 32;
      const float* Xr = &Xlds[row][q * 32];
#pragma unroll
      for (int k4 = 0; k4 < 8; ++k4) {
        fx4 rv = *(const fx4*)(Rr + k4 * 4);
        const fx4 qv = *(const fx4*)(qp + k4 * 4);
        const fx4 xv = *(const fx4*)(Xr + k4 * 4);
        fx4 yv;
#pragma unroll
        for (int j = 0; j < 4; ++j) {
          rv[j] += qv[j];
          lsum = fmaf(rv[j], rv[j], lsum);
          yv[j] = xv[j] + rv[j];
        }
        *(fx4*)(yout + gb + k4 * 4) = yv;
      }
    }
  }

#pragma unroll
  for (int m = 32; m >= 1; m >>= 1) lsum += __shfl_xor(lsum, m, 64);
  if (lane == 0) atomicAdd(lossacc, lsum * (1.25f / 4194304.f));  // 1.25/(N*D)
}

extern "C" void kernel_launch(void* const* d_in, const int* in_sizes, int n_in,
                              void* d_out, int out_size, void* d_ws, size_t ws_size,
                              hipStream_t stream) {
  const float* x = (const float*)d_in[0];     // [32768,128]
  const float* cbf = (const float*)d_in[1];   // [4,1024,128]
  float* y = (float*)d_out;
  float* lossout = y + (out_size - 1);
  u16* cbt = (u16*)d_ws;                      // 1 MiB k-major bf16 codebook

  rvq_prep<<<256, 64, 0, stream>>>(cbf, cbt, lossout);
  rvq_main<<<512, 256, 0, stream>>>(x, cbf, cbt, y, lossout);
}